// Round 1
// baseline (409.886 us; speedup 1.0000x reference)
//
#include <hip/hip_runtime.h>
#include <hip/hip_bf16.h>
#include <cstdint>

#define D_MODEL 2048
#define D_REC   384
#define NPROJ   1152          // 3*D_REC
#define BATCH   4
#define SEQ     4096
#define M_TOTAL (BATCH*SEQ)   // 16384
#define CHUNK   64
#define NCHUNK  (SEQ/CHUNK)   // 64

typedef __attribute__((ext_vector_type(8))) short  short8;
typedef __attribute__((ext_vector_type(4))) float  f32x4;

// ---------------------------------------------------------------- convert
__device__ __forceinline__ uint16_t f2bf(float x) {
    __hip_bfloat16 h = __float2bfloat16(x);
    return *reinterpret_cast<uint16_t*>(&h);
}

__global__ void cvt_bf16(const float* __restrict__ src, uint16_t* __restrict__ dst, long n) {
    long i = ((long)blockIdx.x * blockDim.x + threadIdx.x) * 4;
    if (i + 3 >= n) return;
    float4 f = *reinterpret_cast<const float4*>(src + i);
    ushort4 o;
    o.x = f2bf(f.x); o.y = f2bf(f.y); o.z = f2bf(f.z); o.w = f2bf(f.w);
    *reinterpret_cast<ushort4*>(dst + i) = o;
}

// ---------------------------------------------------------------- GEMM
// C[m][n] = sum_k A[m][k] * B[n][k]    (A,B bf16 K-major; C fp32)
// tile 128x128, BK=32, 256 threads (4 waves, 2x2), each wave 64x64 = 4x4 mfma tiles
__device__ __forceinline__ void gload_lds16(const uint16_t* g, uint16_t* l) {
    __builtin_amdgcn_global_load_lds(
        (__attribute__((address_space(1))) void*)g,
        (__attribute__((address_space(3))) void*)l,
        16, 0, 0);
}

__launch_bounds__(256)
__global__ void gemm_bf16nt(const uint16_t* __restrict__ A,   // [16384][2048]
                            const uint16_t* __restrict__ Bm,  // [1152][2048]
                            float* __restrict__ C)            // [16384][1152]
{
    __shared__ __align__(16) uint16_t As[128 * 32];
    __shared__ __align__(16) uint16_t Bs[128 * 32];

    const int tid  = threadIdx.x;
    const int wave = tid >> 6;
    const int lane = tid & 63;
    const int m0 = blockIdx.x * 128;
    const int n0 = blockIdx.y * 128;
    const int wm = (wave >> 1) * 64;
    const int wn = (wave & 1) * 64;

    const int q  = lane >> 4;     // quad 0..3
    const int lm = lane & 15;

    f32x4 acc[4][4];
#pragma unroll
    for (int i = 0; i < 4; ++i)
#pragma unroll
        for (int j = 0; j < 4; ++j) acc[i][j] = (f32x4){0.f, 0.f, 0.f, 0.f};

    // staging: per op, wave covers 16 rows (lane: row=l>>2, 16B chunk=(l&3))
    const int srow  = wave * 16 + (lane >> 2);     // 0..63
    const int soff8 = (lane & 3) * 8;              // element offset within row

    for (int k0 = 0; k0 < D_MODEL; k0 += 32) {
        // A tile: rows m0..m0+127, cols k0..k0+31
        gload_lds16(A + (long)(m0 + srow)      * D_MODEL + k0 + soff8, &As[(wave * 16) * 32]);
        gload_lds16(A + (long)(m0 + 64 + srow) * D_MODEL + k0 + soff8, &As[(64 + wave * 16) * 32]);
        gload_lds16(Bm + (long)(n0 + srow)      * D_MODEL + k0 + soff8, &Bs[(wave * 16) * 32]);
        gload_lds16(Bm + (long)(n0 + 64 + srow) * D_MODEL + k0 + soff8, &Bs[(64 + wave * 16) * 32]);
        __syncthreads();

        short8 af[4], bf[4];
#pragma unroll
        for (int mt = 0; mt < 4; ++mt)
            af[mt] = *reinterpret_cast<const short8*>(&As[(wm + mt * 16 + lm) * 32 + q * 8]);
#pragma unroll
        for (int nt = 0; nt < 4; ++nt)
            bf[nt] = *reinterpret_cast<const short8*>(&Bs[(wn + nt * 16 + lm) * 32 + q * 8]);
#pragma unroll
        for (int mt = 0; mt < 4; ++mt)
#pragma unroll
            for (int nt = 0; nt < 4; ++nt)
                acc[mt][nt] = __builtin_amdgcn_mfma_f32_16x16x32_bf16(af[mt], bf[nt], acc[mt][nt], 0, 0, 0);
        __syncthreads();
    }

    // epilogue: D[m = q*4 + r][n = lm]
#pragma unroll
    for (int mt = 0; mt < 4; ++mt) {
#pragma unroll
        for (int nt = 0; nt < 4; ++nt) {
            const int row = m0 + wm + mt * 16 + q * 4;
            const int col = n0 + wn + nt * 16 + lm;
#pragma unroll
            for (int r = 0; r < 4; ++r)
                C[(long)(row + r) * NPROJ + col] = acc[mt][nt][r];
        }
    }
}

// ---------------------------------------------------------------- intra-chunk scan
// grid (NCHUNK, BATCH), block 384 (= D_REC). Replicates reference chunk math:
// cum_log += log(max(a,1e-10)); cum_decay = exp(cum_log);
// cum_w += sig / max(cum_decay,1e-10); intra = cum_decay * cum_w
__global__ void intra_scan(const float* __restrict__ aiv, const float* __restrict__ bias,
                           float* __restrict__ out_intra,  // d_out [B][S][D]
                           float* __restrict__ cumdec,     // ws    [B][S][D]
                           float* __restrict__ ctd,        // [B][NCHUNK][D]
                           float* __restrict__ cfs)        // [B][NCHUNK][D]
{
    const int d = threadIdx.x;
    const int c = blockIdx.x;
    const int b = blockIdx.y;
    const float bias_d = bias[d];

    float cum_log = 0.f, cum_w = 0.f, cum_decay = 1.f, intra = 0.f;
    const long rowbase = ((long)b * SEQ + (long)c * CHUNK) * NPROJ;
    const long obase   = ((long)b * SEQ + (long)c * CHUNK) * D_REC;

    for (int t = 0; t < CHUNK; ++t) {
        const long r = rowbase + (long)t * NPROJ;
        const float ap = aiv[r + d];
        const float ip = aiv[r + D_REC + d];
        const float v  = aiv[r + 2 * D_REC + d];

        const float a = 1.f / (1.f + expf(-(ap + bias_d)));
        const float g = 1.f / (1.f + expf(-ip));
        const float sig = sqrtf(fmaxf(1.f - a * a, 1e-8f)) * (g * v);

        cum_log += logf(fmaxf(a, 1e-10f));
        cum_decay = expf(cum_log);
        cum_w += sig / fmaxf(cum_decay, 1e-10f);
        intra = cum_decay * cum_w;

        out_intra[obase + (long)t * D_REC + d] = intra;
        cumdec[obase + (long)t * D_REC + d]    = cum_decay;
    }
    const long cb = ((long)b * NCHUNK + c) * D_REC + d;
    ctd[cb] = cum_decay;
    cfs[cb] = intra;
}

// ---------------------------------------------------------------- cross-chunk scan
__global__ void cross_scan(const float* __restrict__ ctd, const float* __restrict__ cfs,
                           float* __restrict__ incoming)  // [B][NCHUNK][D]
{
    const int d = threadIdx.x;
    const int b = blockIdx.x;
    float cl = 0.f, cw = 0.f;
    incoming[(long)b * NCHUNK * D_REC + d] = 0.f;
    for (int c = 0; c < NCHUNK; ++c) {
        const long idx = ((long)b * NCHUNK + c) * D_REC + d;
        const float td = ctd[idx];
        const float fs = cfs[idx];
        cl += logf(fmaxf(td, 1e-10f));
        const float cd = expf(cl);
        cw += fs / fmaxf(cd, 1e-10f);
        if (c + 1 < NCHUNK) incoming[idx + D_REC] = cd * cw;
    }
}

// ---------------------------------------------------------------- cross contribution
__global__ void add_cross(float* __restrict__ out, const float* __restrict__ cumdec,
                          const float* __restrict__ incoming)
{
    const int d = threadIdx.x;
    const int s = blockIdx.x & (SEQ - 1);
    const int b = blockIdx.x >> 12;
    const long i = (long)blockIdx.x * D_REC + d;
    out[i] += cumdec[i] * incoming[((long)b * NCHUNK + (s >> 6)) * D_REC + d];
}

// ---------------------------------------------------------------- launch
extern "C" void kernel_launch(void* const* d_in, const int* in_sizes, int n_in,
                              void* d_out, int out_size, void* d_ws, size_t ws_size,
                              hipStream_t stream) {
    const float* x  = (const float*)d_in[0];   // [4][4096][2048]
    const float* W  = (const float*)d_in[1];   // [1152][2048]
    const float* db = (const float*)d_in[2];   // [384]
    float* out = (float*)d_out;                // [4][4096][384]

    char* ws = (char*)d_ws;
    // workspace layout (bytes); cumdec overlays xb (dead after GEMM). peak ~147.3 MB
    float*    aiv    = (float*)   (ws + 0);                        // 75,497,472 B
    uint16_t* xb     = (uint16_t*)(ws + 75497472L);                // 67,108,864 B
    uint16_t* Wb     = (uint16_t*)(ws + 142606336L);               //  4,718,592 B
    float*    cumdec = (float*)   (ws + 75497472L);                // 25,165,824 B (reuse)
    float*    ctd    = (float*)   (ws + 100663296L);               //    393,216 B
    float*    cfs    = (float*)   (ws + 101056512L);               //    393,216 B
    float*    inc    = (float*)   (ws + 101449728L);               //    393,216 B

    // 1. convert x, W to bf16 (K-major both)
    {
        const long nx = (long)M_TOTAL * D_MODEL;       // 33,554,432
        cvt_bf16<<<(int)(nx / (4 * 256)), 256, 0, stream>>>(x, xb, nx);
        const long nw = (long)NPROJ * D_MODEL;         // 2,359,296
        cvt_bf16<<<(int)(nw / (4 * 256)), 256, 0, stream>>>(W, Wb, nw);
    }

    // 2. aiv = x . W^T  via bf16 MFMA
    gemm_bf16nt<<<dim3(M_TOTAL / 128, NPROJ / 128), 256, 0, stream>>>(xb, Wb, aiv);

    // 3. intra-chunk scan (+ pointwise gates), writes intra into d_out
    intra_scan<<<dim3(NCHUNK, BATCH), D_REC, 0, stream>>>(aiv, db, out, cumdec, ctd, cfs);

    // 4. cross-chunk scan
    cross_scan<<<BATCH, D_REC, 0, stream>>>(ctd, cfs, inc);

    // 5. add cross contribution
    add_cross<<<BATCH * SEQ, D_REC, 0, stream>>>(out, cumdec, inc);
}

// Round 2
// 329.434 us; speedup vs baseline: 1.2442x; 1.2442x over previous
//
#include <hip/hip_runtime.h>
#include <hip/hip_bf16.h>
#include <cstdint>

#define D_MODEL 2048
#define D_REC   384
#define NPROJ   1152          // 3*D_REC
#define BATCH   4
#define SEQ     4096
#define M_TOTAL (BATCH*SEQ)   // 16384
#define CHUNK   64
#define NCHUNK  (SEQ/CHUNK)   // 64

typedef __attribute__((ext_vector_type(8))) short  short8;
typedef __attribute__((ext_vector_type(4))) float  f32x4;

__device__ __forceinline__ float rcpf(float x) { return __builtin_amdgcn_rcpf(x); }

// ---------------------------------------------------------------- convert
__device__ __forceinline__ uint16_t f2bf(float x) {
    __hip_bfloat16 h = __float2bfloat16(x);
    return *reinterpret_cast<uint16_t*>(&h);
}

__global__ void cvt_bf16(const float* __restrict__ src, uint16_t* __restrict__ dst, long n) {
    long i = ((long)blockIdx.x * blockDim.x + threadIdx.x) * 4;
    if (i + 3 >= n) return;
    float4 f = *reinterpret_cast<const float4*>(src + i);
    ushort4 o;
    o.x = f2bf(f.x); o.y = f2bf(f.y); o.z = f2bf(f.z); o.w = f2bf(f.w);
    *reinterpret_cast<ushort4*>(dst + i) = o;
}

// ---------------------------------------------------------------- GEMM
// C[m][n] = sum_k A[m][k]*B[n][k].  128x128 tile, BK=64, 4 waves (2x2).
// XOR-swizzled LDS: LDS[r][c] = G[r][c ^ (r&7)] (chunks of 8 bf16 = 16B).
// Swizzle applied on the GLOBAL address so global_load_lds dest stays
// base + lane*16 (wave-uniform base requirement).
__device__ __forceinline__ void gload_lds16(const uint16_t* g, uint16_t* l) {
    __builtin_amdgcn_global_load_lds(
        (__attribute__((address_space(1))) void*)g,
        (__attribute__((address_space(3))) void*)l,
        16, 0, 0);
}

__launch_bounds__(256)
__global__ void gemm_bf16nt(const uint16_t* __restrict__ A,   // [16384][2048]
                            const uint16_t* __restrict__ Bm,  // [1152][2048]
                            float* __restrict__ C)            // [16384][1152]
{
    __shared__ __align__(16) uint16_t As[128 * 64];
    __shared__ __align__(16) uint16_t Bs[128 * 64];

    const int tid  = threadIdx.x;
    const int wave = tid >> 6;
    const int lane = tid & 63;
    const int m0 = blockIdx.x * 128;
    const int n0 = blockIdx.y * 128;
    const int wm = (wave >> 1) * 64;
    const int wn = (wave & 1) * 64;

    const int q  = lane >> 4;     // quad 0..3
    const int lm = lane & 15;
    const int h  = lm & 7;        // row&7 for fragment rows

    // staging lane mapping: 8 rows x 8 chunks per wave-op
    const int r_l = lane >> 3;            // 0..7 row-in-segment
    const int cg  = (lane & 7) ^ r_l;     // swizzled global chunk

    f32x4 acc[4][4];
#pragma unroll
    for (int i = 0; i < 4; ++i)
#pragma unroll
        for (int j = 0; j < 4; ++j) acc[i][j] = (f32x4){0.f, 0.f, 0.f, 0.f};

    const long arow = (long)(m0 + wave * 32 + r_l) * D_MODEL + cg * 8;
    const long brow = (long)(n0 + wave * 32 + r_l) * D_MODEL + cg * 8;

    for (int k0 = 0; k0 < D_MODEL; k0 += 64) {
#pragma unroll
        for (int j = 0; j < 4; ++j) {
            gload_lds16(A  + arow + (long)j * 8 * D_MODEL + k0, &As[(wave * 32 + j * 8) * 64]);
            gload_lds16(Bm + brow + (long)j * 8 * D_MODEL + k0, &Bs[(wave * 32 + j * 8) * 64]);
        }
        __syncthreads();

#pragma unroll
        for (int s = 0; s < 2; ++s) {
            short8 af[4], bfr[4];
#pragma unroll
            for (int mt = 0; mt < 4; ++mt)
                af[mt] = *reinterpret_cast<const short8*>(
                    &As[(wm + mt * 16 + lm) * 64 + (((s * 4 + q) ^ h) * 8)]);
#pragma unroll
            for (int nt = 0; nt < 4; ++nt)
                bfr[nt] = *reinterpret_cast<const short8*>(
                    &Bs[(wn + nt * 16 + lm) * 64 + (((s * 4 + q) ^ h) * 8)]);
#pragma unroll
            for (int mt = 0; mt < 4; ++mt)
#pragma unroll
                for (int nt = 0; nt < 4; ++nt)
                    acc[mt][nt] = __builtin_amdgcn_mfma_f32_16x16x32_bf16(af[mt], bfr[nt], acc[mt][nt], 0, 0, 0);
        }
        __syncthreads();
    }

    // epilogue: D[m = q*4 + r][n = lm]
#pragma unroll
    for (int mt = 0; mt < 4; ++mt) {
#pragma unroll
        for (int nt = 0; nt < 4; ++nt) {
            const int row = m0 + wm + mt * 16 + q * 4;
            const int col = n0 + wn + nt * 16 + lm;
#pragma unroll
            for (int r = 0; r < 4; ++r)
                C[(long)(row + r) * NPROJ + col] = acc[mt][nt][r];
        }
    }
}

// ---------------------------------------------------------------- intra-chunk scan
// grid (NCHUNK, BATCH, 3), block 128. Running clipped product == exp(cumsum(log(clip)))
// (identical incl. underflow->0). Stores cumdec & cumw; final kernel combines.
__global__ void intra_scan(const float* __restrict__ aiv, const float* __restrict__ bias,
                           float* __restrict__ cumw_out,  // [B][S][D]
                           float* __restrict__ cumdec,    // [B][S][D]
                           float* __restrict__ ctd,       // [B][NCHUNK][D]
                           float* __restrict__ cfs)       // [B][NCHUNK][D]
{
    const int d = blockIdx.z * 128 + threadIdx.x;
    const int c = blockIdx.x;
    const int b = blockIdx.y;
    const float bias_d = bias[d];

    const long rowbase = ((long)b * SEQ + (long)c * CHUNK) * NPROJ;
    const long obase   = ((long)b * SEQ + (long)c * CHUNK) * D_REC;

    float cd = 1.f, cw = 0.f;

    // prefetch t=0
    float ap = aiv[rowbase + d];
    float ip = aiv[rowbase + D_REC + d];
    float vv = aiv[rowbase + 2 * D_REC + d];

    for (int t = 0; t < CHUNK; ++t) {
        float ap_n, ip_n, vv_n;
        if (t + 1 < CHUNK) {
            const long rn = rowbase + (long)(t + 1) * NPROJ;
            ap_n = aiv[rn + d];
            ip_n = aiv[rn + D_REC + d];
            vv_n = aiv[rn + 2 * D_REC + d];
        }
        const float a = rcpf(1.f + __expf(-(ap + bias_d)));
        const float g = rcpf(1.f + __expf(-ip));
        const float sig = sqrtf(fmaxf(1.f - a * a, 1e-8f)) * (g * vv);

        cd *= fmaxf(a, 1e-10f);
        cw += sig * rcpf(fmaxf(cd, 1e-10f));

        cumdec[obase + (long)t * D_REC + d]   = cd;
        cumw_out[obase + (long)t * D_REC + d] = cw;

        ap = ap_n; ip = ip_n; vv = vv_n;
    }
    const long cb = ((long)b * NCHUNK + c) * D_REC + d;
    ctd[cb] = cd;
    cfs[cb] = cd * cw;
}

// ---------------------------------------------------------------- cross-chunk scan
__global__ void cross_scan(const float* __restrict__ ctd, const float* __restrict__ cfs,
                           float* __restrict__ incoming)  // [B][NCHUNK][D]
{
    const int d = threadIdx.x;
    const int b = blockIdx.x;
    float cdk = 1.f, cwk = 0.f;
    incoming[(long)b * NCHUNK * D_REC + d] = 0.f;
#pragma unroll 4
    for (int c = 0; c < NCHUNK; ++c) {
        const long idx = ((long)b * NCHUNK + c) * D_REC + d;
        const float td = ctd[idx];
        const float fs = cfs[idx];
        cdk *= fmaxf(td, 1e-10f);
        cwk += fs * rcpf(fmaxf(cdk, 1e-10f));
        if (c + 1 < NCHUNK) incoming[idx + D_REC] = cdk * cwk;
    }
}

// ---------------------------------------------------------------- final combine
// out = cumdec * (cumw + incoming[b][s/64][d]), vectorized float4
__global__ void final_combine(const float* __restrict__ cumdec, const float* __restrict__ cumw,
                              const float* __restrict__ inc, float* __restrict__ out)
{
    const long i = ((long)blockIdx.x * blockDim.x + threadIdx.x) * 4;
    const float4 cd = *reinterpret_cast<const float4*>(cumdec + i);
    const float4 cw = *reinterpret_cast<const float4*>(cumw + i);
    const long chunk = i / ((long)D_REC * CHUNK);   // = b*64 + s/64
    const int  dd    = (int)(i % D_REC);
    const float4 ic = *reinterpret_cast<const float4*>(inc + chunk * D_REC + dd);
    float4 o;
    o.x = cd.x * (cw.x + ic.x);
    o.y = cd.y * (cw.y + ic.y);
    o.z = cd.z * (cw.z + ic.z);
    o.w = cd.w * (cw.w + ic.w);
    *reinterpret_cast<float4*>(out + i) = o;
}

// ---------------------------------------------------------------- launch
extern "C" void kernel_launch(void* const* d_in, const int* in_sizes, int n_in,
                              void* d_out, int out_size, void* d_ws, size_t ws_size,
                              hipStream_t stream) {
    const float* x  = (const float*)d_in[0];   // [4][4096][2048]
    const float* W  = (const float*)d_in[1];   // [1152][2048]
    const float* db = (const float*)d_in[2];   // [384]
    float* out = (float*)d_out;                // [4][4096][384]

    char* ws = (char*)d_ws;
    // layout (bytes): aiv 75.5MB | xb 64MB (dead after GEMM; cumdec+cumw overlay) | Wb 4.5MB
    float*    aiv    = (float*)   (ws + 0);                 // 75,497,472 B
    uint16_t* xb     = (uint16_t*)(ws + 75497472L);         // 67,108,864 B
    uint16_t* Wb     = (uint16_t*)(ws + 142606336L);        //  4,718,592 B
    float*    cumdec = (float*)   (ws + 75497472L);         // 25,165,824 B (overlays xb)
    float*    cumw   = (float*)   (ws + 100663296L);        // 25,165,824 B (overlays xb)
    float*    ctd    = (float*)   (ws + 125829120L);        //    393,216 B
    float*    cfs    = (float*)   (ws + 126222336L);        //    393,216 B
    float*    inc    = (float*)   (ws + 126615552L);        //    393,216 B

    // 1. convert x, W to bf16
    {
        const long nx = (long)M_TOTAL * D_MODEL;
        cvt_bf16<<<(int)(nx / (4 * 256)), 256, 0, stream>>>(x, xb, nx);
        const long nw = (long)NPROJ * D_MODEL;
        cvt_bf16<<<(int)(nw / (4 * 256)), 256, 0, stream>>>(W, Wb, nw);
    }

    // 2. aiv = x . W^T via bf16 MFMA
    gemm_bf16nt<<<dim3(M_TOTAL / 128, NPROJ / 128), 256, 0, stream>>>(xb, Wb, aiv);

    // 3. intra-chunk scan (gates + running product), writes cumdec/cumw
    intra_scan<<<dim3(NCHUNK, BATCH, 3), 128, 0, stream>>>(aiv, db, cumw, cumdec, ctd, cfs);

    // 4. cross-chunk scan
    cross_scan<<<BATCH, D_REC, 0, stream>>>(ctd, cfs, inc);

    // 5. combine: out = cumdec * (cumw + incoming)
    final_combine<<<(int)((long)M_TOTAL * D_REC / (4 * 256)), 256, 0, stream>>>(cumdec, cumw, inc, out);
}